// Round 6
// baseline (100.485 us; speedup 1.0000x reference)
//
#include <hip/hip_runtime.h>
#include <hip/hip_bf16.h>

// input_data:       (B=16, S=4096, C=256) fp32
// shifting_weights: (B=16, D=1024)        fp32
// output:           (B=16, D=1024, C=256) fp32
// out[b,d,c] = sum_s exp(-((s+1) - ((d+1)+w[b,d])*4)^2) / AMP * input[b,s,c]
//
// R6: async LDS staging via __builtin_amdgcn_global_load_lds.
// Lesson from R3/R4/R5: in-flight load bytes (not traffic volume) is the
// binder, and VGPR-landing-buffer capacity caps it (~340 KB/CU). global_load
// _lds uses NO VGPR destinations -> LDS (64 KB/block) becomes the in-flight
// buffer, while also deduplicating the window fetch across the block's 8 d's
// (285 MB -> ~115 MB vector-side traffic).
//
// Structure: block = 8 waves = 8 consecutive d's of one b. Stage the union
// window [rint(cmin)-8, rint(cmax)+8] (typ ~56 rows, cap 64 = 64 KB LDS) with
// width-16 DMA (1 row = 1 KB = one wave-instr), one __syncthreads (drains
// vmcnt), then each wave does its 17 taps from LDS. Taps outside the staged
// window (~1-2% of blocks: weight-spread outliers, or s outside [1,S]) fall
// back to direct global reads -- wave-uniform branch, exact.
// 64 KB LDS -> 2 blocks/CU: one stages (async) while the other computes.

constexpr int B = 16;
constexpr int S = 4096;
constexpr int C = 256;
constexpr int D = 1024;
constexpr float SCALING = (float)S / (float)D;   // 4.0
constexpr float INV_AMP = 1.0f / 1.772637204826652f;
constexpr int RAD   = 8;
constexpr int TAPS  = 2 * RAD + 1;   // 17
constexpr int GB    = 8;             // d's per block (1 per wave)
constexpr int WPB   = 8;             // waves per block
constexpr int HROWS = 64;            // staged rows -> 64 KB LDS
constexpr int NUM_XCD = 8;

typedef float f32x4 __attribute__((ext_vector_type(4)));

__device__ __forceinline__ void stage_row16(const float* g, float* l) {
    // width=16: each lane DMAs 16 B; LDS dest = wave-uniform base + lane*16.
    __builtin_amdgcn_global_load_lds(
        (const __attribute__((address_space(1))) void*)g,
        (__attribute__((address_space(3))) void*)l,
        16, 0, 0);
}

__global__ __launch_bounds__(512) void shifting_kernel(
    const float* __restrict__ input,
    const float* __restrict__ wts,
    float* __restrict__ out)
{
    __shared__ float buf[HROWS * C];   // 64 KB, row r at buf + r*256

    const int wave = threadIdx.x >> 6;
    const int lane = threadIdx.x & 63;

    // XCD-contiguity swizzle (kept from R3: contiguous d-span per XCD L2).
    const int per_xcd = gridDim.x >> 3;              // 2048/8 = 256
    const int pblk = blockIdx.x;
    const int lblk = (pblk & (NUM_XCD - 1)) * per_xcd + (pblk >> 3);

    const int gidx0 = lblk * GB;                     // first flat b*D+d
    const int b     = gidx0 >> 10;                   // / D
    const int d0    = gidx0 & (D - 1);               // aligned: all 8 same b

    // Block-uniform center min/max + this wave's center (redundant per thread;
    // uniform addresses -> scalar loads).
    float cmin = 1e30f, cmax = -1e30f, cme = 0.0f;
#pragma unroll
    for (int i = 0; i < GB; ++i) {
        float ci = ((float)(d0 + i + 1) + wts[gidx0 + i]) * SCALING;
        cmin = fminf(cmin, ci);
        cmax = fmaxf(cmax, ci);
        cme  = (i == wave) ? ci : cme;
    }

    const int lo = max(1, (int)rintf(cmin) - RAD);
    const int hi = min(S, (int)rintf(cmax) + RAD);
    const unsigned cstage = (unsigned)max(min(hi - lo + 1, HROWS), 0);

    // ---- Stage: rows [lo, lo+cstage-1]; wave w stages rows w, w+8, ... ----
    const float* stage_g = input + (size_t)b * S * C
                                 + (size_t)(lo - 1) * C + (lane << 2);
    for (int r = wave; r < (int)cstage; r += WPB)
        stage_row16(stage_g + (size_t)r * C, buf + r * C);

    __syncthreads();   // drains vmcnt -> staged data visible

    // ---- Compute: this wave's 17 taps ----
    const float c  = cme;
    const int   s0 = (int)rintf(c) - RAD;
    const float* rb = input + (size_t)b * S * C + (lane << 2);

    f32x4 acc = {0.f, 0.f, 0.f, 0.f};
#pragma unroll
    for (int k = 0; k < TAPS; ++k) {
        int s = s0 + k;
        float dd = (float)s - c;
        float g  = __expf(-dd * dd);
        unsigned u = (unsigned)(s - lo);   // wraps for s < lo -> global path
        f32x4 v;
        if (u < cstage) {                  // wave-uniform branch
            v = *(const f32x4*)(buf + (size_t)u * C + (lane << 2));
        } else {
            int sc = min(max(s, 1), S);
            v = *(const f32x4*)(rb + (size_t)(sc - 1) * C);
            g = (s >= 1 && s <= S) ? g : 0.0f;   // exact: excluded taps are 0
        }
        acc += g * v;
    }

    f32x4 r = acc * INV_AMP;
    __builtin_nontemporal_store(
        r, (f32x4*)(out + (size_t)(gidx0 + wave) * C + (lane << 2)));
}

extern "C" void kernel_launch(void* const* d_in, const int* in_sizes, int n_in,
                              void* d_out, int out_size, void* d_ws, size_t ws_size,
                              hipStream_t stream) {
    const float* input = (const float*)d_in[0];
    const float* wts   = (const float*)d_in[1];
    float* out         = (float*)d_out;

    dim3 grid(B * D / GB);   // 2048 blocks: 8 waves/block, 1 d per wave
    dim3 block(WPB * 64);    // 512 threads
    shifting_kernel<<<grid, block, 0, stream>>>(input, wts, out);
}